// Round 8
// baseline (104.723 us; speedup 1.0000x reference)
//
#include <hip/hip_runtime.h>

#define NPTS  4096
#define MQ    16384
#define CF    64
#define GRIDC 32
#define NCELLS (GRIDC * GRIDC)   // 1024
#define CAP   20                 // lambda = 4 pts/cell; P(any cell > 20) ~ 2e-6
#define INVCELL 0.625f           // 1/1.6, exact in binary; cell 1.6 > radius 1.0
#define SENT  0x7fffffff
#define TPB   256
#define NBLK  512
#define QPB   (MQ / NBLK)        // 32 queries/block, 8 per wave

// MEASUREMENT ROUND: identical kernel body to R7, launched TWICE per call.
// The kernel is a pure function of d_in (second launch rewrites identical
// bytes), so this is graph/tripwire-safe and gives t_kernel = dur - 83.9 to
// arbitrate between "kernel ~31us (cross-round overhead fit)" vs "kernel ~4us
// (instruction arithmetic)" before committing to an optimization direction.
__global__ __launch_bounds__(TPB, 2) void k_all(
    const float* __restrict__ pillar,   // M x 64
    const int*   __restrict__ coors,    // M x 4 (b, z, y, x)
    const float* __restrict__ segf,     // N x 64
    const float* __restrict__ segp,     // N x 3
    float* __restrict__ out)            // M x 64
{
    __shared__ float2 sxy[NPTS];                       // 32 KB
    __shared__ int scnt[NCELLS];                       // 4 KB
    __shared__ unsigned short sbkt[NCELLS * CAP];      // 40 KB  (total 76 KB)

    const int tid = threadIdx.x;

    for (int c = tid; c < NCELLS; c += TPB) scnt[c] = 0;
    __syncthreads();

    // Build: load points, stash xy, bin id into cell bucket.
    for (int p = tid; p < NPTS; p += TPB) {
        const float px = segp[3 * p + 0];
        const float py = segp[3 * p + 1];
        sxy[p] = make_float2(px, py);
        int ix = (int)(px * INVCELL);
        int iy = (int)((py + 25.6f) * INVCELL);
        ix = min(max(ix, 0), GRIDC - 1);
        iy = min(max(iy, 0), GRIDC - 1);
        const int slot = atomicAdd(&scnt[iy * GRIDC + ix], 1);
        if (slot < CAP) sbkt[(iy * GRIDC + ix) * CAP + slot] = (unsigned short)p;
    }
    __syncthreads();

    // Queries: wave-per-query x8, all data in LDS.
    const int wave = tid >> 6;
    const int lane = tid & 63;
    const int lc = lane / 20;            // window-cell sub-index 0..2 (3 = idle)
    const int sl = lane - lc * 20;       // slot within cell

    for (int it = 0; it < QPB / 4; ++it) {
        const int q = blockIdx.x * QPB + wave * (QPB / 4) + it;
        const int cx = coors[4 * q + 3];
        const int cy = coors[4 * q + 2];
        // (c + 0.5) * 0.16 + pc_range — mul then add, NO fma (bit-exact)
        const float qx = __fadd_rn(__fmul_rn(__fadd_rn((float)cx, 0.5f), 0.16f), 0.0f);
        const float qy = __fadd_rn(__fmul_rn(__fadd_rn((float)cy, 0.5f), 0.16f), -25.6f);
        const int icx = (int)(qx * INVCELL);
        const int icy = (int)((qy + 25.6f) * INVCELL);
        // 3x3 window covers the r=1.0 ball (cell 1.6, margin 0.6 >> f32 eps);
        // cells only pick a candidate SUPERSET — exactness lives in d2 < 1.

        // Each lane sees at most one candidate per batch; keep them sorted.
        int c0 = SENT, c1 = SENT, c2 = SENT;
#pragma unroll
        for (int b = 0; b < 3; ++b) {
            int cand = SENT;
            if (lc < 3) {
                const int j = 3 * b + lc;          // window cell 0..8
                const int iy2 = icy + j / 3 - 1;
                const int ix2 = icx + j % 3 - 1;
                if (ix2 >= 0 && ix2 < GRIDC && iy2 >= 0 && iy2 < GRIDC) {
                    const int cell = iy2 * GRIDC + ix2;
                    int cnt = scnt[cell];
                    cnt = cnt > CAP ? CAP : cnt;
                    if (sl < cnt) {
                        const int id = sbkt[cell * CAP + sl];
                        const float2 e = sxy[id];
                        const float dx = __fsub_rn(qx, e.x);
                        const float dy = __fsub_rn(qy, e.y);
                        const float d2 = __fadd_rn(__fmul_rn(dx, dx), __fmul_rn(dy, dy));
                        if (d2 < 1.0f) cand = id;
                    }
                }
            }
            // sorted insert into per-lane list (ids unique)
            if (cand < c2) {
                if (cand < c1) {
                    c2 = c1;
                    if (cand < c0) { c1 = c0; c0 = cand; } else { c1 = cand; }
                } else { c2 = cand; }
            }
        }

        // Global 4 smallest: 4 extraction rounds over per-lane minimum.
        int r0 = SENT, r1 = SENT, r2 = SENT, r3 = SENT;
#pragma unroll
        for (int r = 0; r < 4; ++r) {
            int v = c0;
            for (int off = 32; off; off >>= 1) v = min(v, __shfl_xor(v, off));
            if (v == SENT) break;                 // wave-uniform
            if (r == 0) r0 = v; else if (r == 1) r1 = v;
            else if (r == 2) r2 = v; else r3 = v; // ascending order by construction
            if (c0 == v) { c0 = c1; c1 = c2; c2 = SENT; }  // pop owner's min
        }

        int i0, i1, i2, i3, flag;
        if (r0 == SENT) {
            i0 = i1 = i2 = i3 = 0; flag = 0;      // no neighbor: ref = zeros
        } else {
            i0 = r0;
            i1 = (r1 == SENT) ? r0 : r1;          // pad with FIRST (= min) index
            i2 = (r2 == SENT) ? r0 : r2;
            i3 = (r3 == SENT) ? r0 : r3;
            flag = (i0 + i1 + i2 + i3) > 0;       // ref: flag = sum(idx) > 0
        }

        float m = 0.0f;
        if (flag) {
            const float a = segf[i0 * CF + lane];
            const float b2 = segf[i1 * CF + lane];
            const float c = segf[i2 * CF + lane];
            const float d = segf[i3 * CF + lane];
            m = fmaxf(fmaxf(a, b2), fmaxf(c, d));
        }
        out[q * CF + lane] = pillar[q * CF + lane] + m;
    }
}

extern "C" void kernel_launch(void* const* d_in, const int* in_sizes, int n_in,
                              void* d_out, int out_size, void* d_ws, size_t ws_size,
                              hipStream_t stream) {
    const float* pillar = (const float*)d_in[0];
    const int*   coors  = (const int*)d_in[1];
    const float* segf   = (const float*)d_in[2];
    const float* segp   = (const float*)d_in[3];
    float* out = (float*)d_out;

    // Launched twice on purpose (both every call — idempotent, deterministic):
    // dur_us - 83.9 isolates the kernel's in-graph cost.
    k_all<<<NBLK, TPB, 0, stream>>>(pillar, coors, segf, segp, out);
    k_all<<<NBLK, TPB, 0, stream>>>(pillar, coors, segf, segp, out);
}

// Round 9
// 70.437 us; speedup vs baseline: 1.4868x; 1.4868x over previous
//
#include <hip/hip_runtime.h>

#define NPTS  4096
#define MQ    16384
#define CF    64
#define GRIDC 32
#define NCELLS (GRIDC * GRIDC)   // 1024
#define CAP   20                 // lambda = 4 pts/cell; P(any cell > 20) ~ 2e-6
#define INVCELL 0.625f           // 1/1.6, exact in binary; cell 1.6 > radius 1.0
#define SENT  0x7fffffff
#define TPB   1024
#define NBLK  512
#define QPB   (MQ / NBLK)        // 32 queries/block
#define WPB   (TPB / 64)         // 16 waves/block
#define QPW   (QPB / WPB)        // 2 queries/wave

// R8 measurement: kernel+gap = 104.7-83.9 = 20.8us, harness floor ~63us.
// Cause of the 20us: 76KB LDS @ TPB=256 -> 8 waves/CU (2/SIMD) -> no latency
// hiding for 8 queries/wave x ~24 serial dependent shuffles each.
// R9: TPB=1024 (32 waves/CU, full), 2 queries/wave, and a 6-stage butterfly
// bitonic merge-4 (depth 6, shuffles independent within a stage) replacing
// the 4x6 serial wave-min extraction.
//
// "First 4 in scan order" == "4 smallest indices of the in-radius set"
// (pad = first found = min index). Min-4 is enumeration-order-independent, so
// LDS-atomic bucket order cannot affect the output: bit-deterministic.
__global__ __launch_bounds__(TPB) void k_all(
    const float* __restrict__ pillar,   // M x 64
    const int*   __restrict__ coors,    // M x 4 (b, z, y, x)
    const float* __restrict__ segf,     // N x 64
    const float* __restrict__ segp,     // N x 3
    float* __restrict__ out)            // M x 64
{
    __shared__ float2 sxy[NPTS];                       // 32 KB
    __shared__ int scnt[NCELLS];                       // 4 KB
    __shared__ unsigned short sbkt[NCELLS * CAP];      // 40 KB  (total 76 KB)

    const int tid = threadIdx.x;

    scnt[tid & (NCELLS - 1)] = 0;                      // NCELLS == 1024 == TPB
    __syncthreads();

    // Build: load points, stash xy, bin id into cell bucket (4 iters).
    for (int p = tid; p < NPTS; p += TPB) {
        const float px = segp[3 * p + 0];
        const float py = segp[3 * p + 1];
        sxy[p] = make_float2(px, py);
        int ix = (int)(px * INVCELL);
        int iy = (int)((py + 25.6f) * INVCELL);
        ix = min(max(ix, 0), GRIDC - 1);
        iy = min(max(iy, 0), GRIDC - 1);
        const int slot = atomicAdd(&scnt[iy * GRIDC + ix], 1);
        if (slot < CAP) sbkt[(iy * GRIDC + ix) * CAP + slot] = (unsigned short)p;
    }
    __syncthreads();

    // Queries: wave-per-query x2, all data in LDS.
    const int wave = tid >> 6;
    const int lane = tid & 63;
    const int lc = lane / 20;            // window-cell sub-index 0..2 (3 = idle)
    const int sl = lane - lc * 20;       // slot within cell

    for (int it = 0; it < QPW; ++it) {
        const int q = blockIdx.x * QPB + wave * QPW + it;
        const int cx = coors[4 * q + 3];
        const int cy = coors[4 * q + 2];
        // (c + 0.5) * 0.16 + pc_range — mul then add, NO fma (bit-exact)
        const float qx = __fadd_rn(__fmul_rn(__fadd_rn((float)cx, 0.5f), 0.16f), 0.0f);
        const float qy = __fadd_rn(__fmul_rn(__fadd_rn((float)cy, 0.5f), 0.16f), -25.6f);
        const int icx = (int)(qx * INVCELL);
        const int icy = (int)((qy + 25.6f) * INVCELL);
        // 3x3 window covers the r=1.0 ball (cell 1.6, margin 0.6 >> f32 eps);
        // cells only pick a candidate SUPERSET — exactness lives in d2 < 1.

        // Each lane sees at most one candidate per batch; keep them sorted.
        int c0 = SENT, c1 = SENT, c2 = SENT;
#pragma unroll
        for (int b = 0; b < 3; ++b) {
            int cand = SENT;
            if (lc < 3) {
                const int j = 3 * b + lc;          // window cell 0..8
                const int iy2 = icy + j / 3 - 1;
                const int ix2 = icx + j % 3 - 1;
                if (ix2 >= 0 && ix2 < GRIDC && iy2 >= 0 && iy2 < GRIDC) {
                    const int cell = iy2 * GRIDC + ix2;
                    int cnt = scnt[cell];
                    cnt = cnt > CAP ? CAP : cnt;
                    if (sl < cnt) {
                        const int id = sbkt[cell * CAP + sl];
                        const float2 e = sxy[id];
                        const float dx = __fsub_rn(qx, e.x);
                        const float dy = __fsub_rn(qy, e.y);
                        const float d2 = __fadd_rn(__fmul_rn(dx, dx), __fmul_rn(dy, dy));
                        if (d2 < 1.0f) cand = id;
                    }
                }
            }
            // sorted insert into per-lane list (ids unique)
            if (cand < c2) {
                if (cand < c1) {
                    c2 = c1;
                    if (cand < c0) { c1 = c0; c0 = cand; } else { c1 = cand; }
                } else { c2 = cand; }
            }
        }

        // Global min-4 via butterfly bitonic merge: each lane carries a sorted
        // ascending 4-list; 6 xor-stages merge partner lists (lower half of a
        // bitonic merge + 2-level cleanup). All lanes end with the answer.
        int v0 = c0, v1 = c1, v2 = c2, v3 = SENT;
#pragma unroll
        for (int off = 1; off < 64; off <<= 1) {
            const int w0 = __shfl_xor(v0, off);
            const int w1 = __shfl_xor(v1, off);
            const int w2 = __shfl_xor(v2, off);
            const int w3 = __shfl_xor(v3, off);
            const int t0 = min(v0, w3);
            const int t1 = min(v1, w2);
            const int t2 = min(v2, w1);
            const int t3 = min(v3, w0);
            const int a0 = min(t0, t2), a2 = max(t0, t2);
            const int a1 = min(t1, t3), a3 = max(t1, t3);
            v0 = min(a0, a1); v1 = max(a0, a1);
            v2 = min(a2, a3); v3 = max(a2, a3);
        }

        int i0, i1, i2, i3, flag;
        if (v0 == SENT) {
            i0 = i1 = i2 = i3 = 0; flag = 0;      // no neighbor: ref = zeros
        } else {
            i0 = v0;
            i1 = (v1 == SENT) ? v0 : v1;          // pad with FIRST (= min) index
            i2 = (v2 == SENT) ? v0 : v2;
            i3 = (v3 == SENT) ? v0 : v3;
            flag = (i0 + i1 + i2 + i3) > 0;       // ref: flag = sum(idx) > 0
        }

        float m = 0.0f;
        if (flag) {
            const float a = segf[i0 * CF + lane];
            const float b2 = segf[i1 * CF + lane];
            const float c = segf[i2 * CF + lane];
            const float d = segf[i3 * CF + lane];
            m = fmaxf(fmaxf(a, b2), fmaxf(c, d));
        }
        out[q * CF + lane] = pillar[q * CF + lane] + m;
    }
}

extern "C" void kernel_launch(void* const* d_in, const int* in_sizes, int n_in,
                              void* d_out, int out_size, void* d_ws, size_t ws_size,
                              hipStream_t stream) {
    const float* pillar = (const float*)d_in[0];
    const int*   coors  = (const int*)d_in[1];
    const float* segf   = (const float*)d_in[2];
    const float* segp   = (const float*)d_in[3];
    float* out = (float*)d_out;

    k_all<<<NBLK, TPB, 0, stream>>>(pillar, coors, segf, segp, out);
}

// Round 10
// 68.379 us; speedup vs baseline: 1.5315x; 1.0301x over previous
//
#include <hip/hip_runtime.h>

#define NPTS  4096
#define MQ    16384
#define CF    64
#define GRIDC 32
#define NCELLS (GRIDC * GRIDC)   // 1024
#define CAP   20                 // lambda = 4 pts/cell; P(any cell > 20) ~ 2e-6
#define INVCELL 0.625f           // 1/1.6, exact in binary; cell 1.6 > radius 1.0
#define SENT16 0xFFFF            // ids <= 4095, so u16 sentinel is safe
#define TPB   1024
#define NBLK  512
#define QPB   (MQ / NBLK)        // 32 queries/block
#define WPB   (TPB / 64)         // 16 waves/block

// Ledger: harness floor 63.1us (R8 double-launch isolation); R9 kernel ~7.3us,
// DS-pipe bound (~33 wave-DS-ops/query x 64 queries/CU). R10: two queries per
// wave (half-wave each) so candidate loads amortize 2x and the butterfly is
// 5 stages; sorted-4 list packed into 2 u32 for transport (2 shuffles/stage);
// float2 epilogue. DS ops/query 33 -> ~14.
//
// "First 4 in scan order" == "4 smallest indices of the in-radius set"
// (pad = first found = min index). Min-4 is enumeration-order-independent, so
// LDS-atomic bucket order cannot affect the output: bit-deterministic.
__global__ __launch_bounds__(TPB) void k_all(
    const float* __restrict__ pillar,   // M x 64
    const int*   __restrict__ coors,    // M x 4 (b, z, y, x)
    const float* __restrict__ segf,     // N x 64
    const float* __restrict__ segp,     // N x 3
    float* __restrict__ out)            // M x 64
{
    __shared__ float2 sxy[NPTS];                       // 32 KB
    __shared__ int scnt[NCELLS];                       // 4 KB
    __shared__ unsigned short sbkt[NCELLS * CAP];      // 40 KB  (total 76 KB)

    const int tid = threadIdx.x;

    scnt[tid & (NCELLS - 1)] = 0;                      // NCELLS == TPB
    __syncthreads();

    // Build: load points, stash xy, bin id into cell bucket (4 iters).
    for (int p = tid; p < NPTS; p += TPB) {
        const float px = segp[3 * p + 0];
        const float py = segp[3 * p + 1];
        sxy[p] = make_float2(px, py);
        int ix = (int)(px * INVCELL);
        int iy = (int)((py + 25.6f) * INVCELL);
        ix = min(max(ix, 0), GRIDC - 1);
        iy = min(max(iy, 0), GRIDC - 1);
        const int slot = atomicAdd(&scnt[iy * GRIDC + ix], 1);
        if (slot < CAP) sbkt[(iy * GRIDC + ix) * CAP + slot] = (unsigned short)p;
    }
    __syncthreads();

    // Two queries per wave: half h = lane>>5 owns query q; candidate batches
    // and shuffle stages are shared wave instructions serving both halves.
    const int wave = tid >> 6;
    const int lane = tid & 63;
    const int h  = lane >> 5;
    const int hl = lane & 31;

    const int q = blockIdx.x * QPB + wave * 2 + h;
    const int2 cc = *(const int2*)(&coors[4 * q + 2]);  // (y, x)
    // (c + 0.5) * 0.16 + pc_range — mul then add, NO fma (bit-exact)
    const float qx = __fadd_rn(__fmul_rn(__fadd_rn((float)cc.y, 0.5f), 0.16f), 0.0f);
    const float qy = __fadd_rn(__fmul_rn(__fadd_rn((float)cc.x, 0.5f), 0.16f), -25.6f);
    const int icx = (int)(qx * INVCELL);
    const int icy = (int)((qy + 25.6f) * INVCELL);
    // 3x3 window covers the r=1.0 ball (cell 1.6, margin 0.6 >> f32 eps);
    // cells only pick a candidate SUPERSET — exactness lives in d2 < 1.

    // 6 batches x 32 lanes cover the 9*20=180 (cell,slot) space exactly once.
    // Per-lane sorted ascending 4-list (a lane sees at most 1 cand/batch).
    int c0 = SENT16, c1 = SENT16, c2 = SENT16, c3 = SENT16;
#pragma unroll
    for (int b = 0; b < 6; ++b) {
        const int s = b * 32 + hl;
        int cand = SENT16;
        if (s < 180) {
            const int j  = s / 20;             // window cell 0..8 (const div)
            const int sl = s - j * 20;         // slot within cell
            const int iy2 = icy + j / 3 - 1;
            const int ix2 = icx + j % 3 - 1;
            if (ix2 >= 0 && ix2 < GRIDC && iy2 >= 0 && iy2 < GRIDC) {
                const int cell = iy2 * GRIDC + ix2;
                int cnt = scnt[cell];
                cnt = cnt > CAP ? CAP : cnt;
                if (sl < cnt) {
                    const int id = sbkt[cell * CAP + sl];
                    const float2 e = sxy[id];
                    const float dx = __fsub_rn(qx, e.x);
                    const float dy = __fsub_rn(qy, e.y);
                    const float d2 = __fadd_rn(__fmul_rn(dx, dx), __fmul_rn(dy, dy));
                    if (d2 < 1.0f) cand = id;
                }
            }
        }
        // sorted insert (ids unique)
        if (cand < c3) {
            if (cand < c2) {
                c3 = c2;
                if (cand < c1) {
                    c2 = c1;
                    if (cand < c0) { c1 = c0; c0 = cand; } else { c1 = cand; }
                } else { c2 = cand; }
            } else { c3 = cand; }
        }
    }

    // Butterfly bitonic merge-4 within each 32-lane half (xor offsets < 32
    // never cross the half boundary). Lists packed 4x16b -> 2 u32 transport.
    unsigned int A = (unsigned int)c0 | ((unsigned int)c1 << 16);
    unsigned int B = (unsigned int)c2 | ((unsigned int)c3 << 16);
#pragma unroll
    for (int off = 1; off < 32; off <<= 1) {
        const unsigned int Ax = (unsigned int)__shfl_xor((int)A, off);
        const unsigned int Bx = (unsigned int)__shfl_xor((int)B, off);
        const int w0 = (int)(Ax & 0xFFFFu), w1 = (int)(Ax >> 16);
        const int w2 = (int)(Bx & 0xFFFFu), w3 = (int)(Bx >> 16);
        const int t0 = min(c0, w3), t1 = min(c1, w2);
        const int t2 = min(c2, w1), t3 = min(c3, w0);
        const int a0 = min(t0, t2), a2 = max(t0, t2);
        const int a1 = min(t1, t3), a3 = max(t1, t3);
        c0 = min(a0, a1); c1 = max(a0, a1);
        c2 = min(a2, a3); c3 = max(a2, a3);
        A = (unsigned int)c0 | ((unsigned int)c1 << 16);
        B = (unsigned int)c2 | ((unsigned int)c3 << 16);
    }

    int i0, i1, i2, i3, flag;
    if (c0 == SENT16) {
        i0 = i1 = i2 = i3 = 0; flag = 0;       // no neighbor: ref = zeros
    } else {
        i0 = c0;
        i1 = (c1 == SENT16) ? c0 : c1;         // pad with FIRST (= min) index
        i2 = (c2 == SENT16) ? c0 : c2;
        i3 = (c3 == SENT16) ? c0 : c3;
        flag = (i0 + i1 + i2 + i3) > 0;        // ref: flag = sum(idx) > 0
    }

    // Epilogue: half-wave per row, float2 per lane (channels 2*hl, 2*hl+1).
    const int col = 2 * hl;
    float2 m2 = make_float2(0.0f, 0.0f);
    if (flag) {
        const float2 a = *(const float2*)(&segf[i0 * CF + col]);
        const float2 b = *(const float2*)(&segf[i1 * CF + col]);
        const float2 c = *(const float2*)(&segf[i2 * CF + col]);
        const float2 d = *(const float2*)(&segf[i3 * CF + col]);
        m2.x = fmaxf(fmaxf(a.x, b.x), fmaxf(c.x, d.x));
        m2.y = fmaxf(fmaxf(a.y, b.y), fmaxf(c.y, d.y));
    }
    const float2 p2 = *(const float2*)(&pillar[q * CF + col]);
    *(float2*)(&out[q * CF + col]) = make_float2(p2.x + m2.x, p2.y + m2.y);
}

extern "C" void kernel_launch(void* const* d_in, const int* in_sizes, int n_in,
                              void* d_out, int out_size, void* d_ws, size_t ws_size,
                              hipStream_t stream) {
    const float* pillar = (const float*)d_in[0];
    const int*   coors  = (const int*)d_in[1];
    const float* segf   = (const float*)d_in[2];
    const float* segp   = (const float*)d_in[3];
    float* out = (float*)d_out;

    k_all<<<NBLK, TPB, 0, stream>>>(pillar, coors, segf, segp, out);
}